// Round 11
// baseline (346.067 us; speedup 1.0000x reference)
//
#include <hip/hip_runtime.h>

#define BB 2
#define NN 32768
#define EN 32768

typedef unsigned int u32;
typedef __attribute__((ext_vector_type(8))) short bf16x8;
typedef __attribute__((ext_vector_type(4))) float f32x4;

union U4 { uint4 u; bf16x8 h; };

#if defined(__has_builtin)
#if __has_builtin(__builtin_amdgcn_cvt_pk_bf16_f32)
#define HAVE_CVT_PK 1
#endif
#endif

#ifdef HAVE_CVT_PK
typedef __attribute__((ext_vector_type(2))) __bf16 bfv2;
__device__ __forceinline__ u32 pk2(float lo, float hi) {
    bfv2 v = __builtin_amdgcn_cvt_pk_bf16_f32(lo, hi);
    return __builtin_bit_cast(u32, v);
}
#else
__device__ __forceinline__ u32 pk2(float lo, float hi) {
    u32 a = __builtin_bit_cast(u32, lo);
    u32 b = __builtin_bit_cast(u32, hi);
    a += 0x7FFFu + ((a >> 16) & 1u);
    b += 0x7FFFu + ((b >> 16) & 1u);
    return (a >> 16) | (b & 0xFFFF0000u);
}
#endif

__device__ __forceinline__ f32x4 MF(bf16x8 a, bf16x8 b, f32x4 c) {
    return __builtin_amdgcn_mfma_f32_16x16x32_bf16(a, b, c, 0, 0, 0);
}
__device__ __forceinline__ f32x4 toC(float4 v) {
    f32x4 r = {v.x, v.y, v.z, v.w};
    return r;
}

// LDS weight swizzle (4-way residual conflict; floor for 16-dword rows).
__device__ __forceinline__ int swz(int rowbase, int q) {
    return rowbase + (((q + (rowbase >> 5)) & 3) << 2);
}

// ---------------------------------------------------------------------------
// Layer epilogue. Bias is already folded into D via the MFMA C operand, so
// relu applies directly. LN = normalize-only (affine folded into weights);
// stats across 4 lanes (n, q=0..3) via THREE PARALLEL shfl_xor (16/32/48) —
// one DS latency instead of two serialized.
// ---------------------------------------------------------------------------
template<bool LN>
__device__ __forceinline__ bf16x8 transform(f32x4 D0, f32x4 D1)
{
    float y0 = fmaxf(D0[0], 0.f), y1 = fmaxf(D0[1], 0.f);
    float y2 = fmaxf(D0[2], 0.f), y3 = fmaxf(D0[3], 0.f);
    float z0 = fmaxf(D1[0], 0.f), z1 = fmaxf(D1[1], 0.f);
    float z2 = fmaxf(D1[2], 0.f), z3 = fmaxf(D1[3], 0.f);
    if (LN) {
        float s = ((y0+y1)+(y2+y3)) + ((z0+z1)+(z2+z3));
        float t = 0.f;
        t = fmaf(y0,y0,t); t = fmaf(y1,y1,t); t = fmaf(y2,y2,t); t = fmaf(y3,y3,t);
        t = fmaf(z0,z0,t); t = fmaf(z1,z1,t); t = fmaf(z2,z2,t); t = fmaf(z3,z3,t);
        float sa = __shfl_xor(s, 16), sb = __shfl_xor(s, 32), sc = __shfl_xor(s, 48);
        float ta = __shfl_xor(t, 16), tb = __shfl_xor(t, 32), tc = __shfl_xor(t, 48);
        s = (s + sa) + (sb + sc);
        t = (t + ta) + (tb + tc);
        float mu  = s * (1.f/32.f);
        float var = fmaf(-mu, mu, t * (1.f/32.f));
        float rs  = rsqrtf(var + 1e-5f);
        float nt  = -mu * rs;
        y0 = fmaf(y0, rs, nt); y1 = fmaf(y1, rs, nt);
        y2 = fmaf(y2, rs, nt); y3 = fmaf(y3, rs, nt);
        z0 = fmaf(z0, rs, nt); z1 = fmaf(z1, rs, nt);
        z2 = fmaf(z2, rs, nt); z3 = fmaf(z3, rs, nt);
    }
    U4 c;
    c.u.x = pk2(y0, z0); c.u.y = pk2(y1, z1);
    c.u.z = pk2(y2, z2); c.u.w = pk2(y3, z3);
    return c.h;
}

// ---------------------------------------------------------------------------
// Block-level staging of packed weights + biases into LDS (swizzled).
// Caller must __syncthreads() after all staging calls.
// WB layout (floats): [0..32) bin | [32..1056) hidden biases | [1056..1072) out
// ---------------------------------------------------------------------------
__device__ __forceinline__ void stage_weights(
    u32* WL, float* WB, const u32* __restrict__ Wp,
    const float* __restrict__ bin, const float* __restrict__ bhid,
    const float* __restrict__ bo, int wtot, int nbo, int tid, int nthr)
{
    for (int C = tid; C * 4 < wtot; C += nthr) {
        int Cp = (C & ~3) | ((C + (C >> 3)) & 3);
        *(uint4*)(WL + Cp*4) = *(const uint4*)(Wp + C*4);
    }
    for (int i = tid; i < 1072; i += nthr) {
        float v;
        if (i < 32)         v = bin[i];
        else if (i < 1056)  v = bhid[i-32];
        else                v = (i-1056 < nbo) ? bo[i-1056] : 0.f;
        WB[i] = v;
    }
}

// ---------------------------------------------------------------------------
// Wave-level deep MLP over G independent 16-element groups; weights/biases
// from LDS. Biases enter through the MFMA C operand (free adds). Depth-2
// weight prefetch + depth-1 bias prefetch. Returns O[g] = final-layer MFMA
// output (bias included, pre-relu).
// WL (pi layout): [Bin 32 x KT*16 dw][Bh 32 x 512 dw][Bo 256 dw]
// ---------------------------------------------------------------------------
template<int KT, int G, bool LN>
__device__ __forceinline__ void mlp_core(
    const bf16x8* bIn, const u32* WL, const float* WB,
    int n, int q, f32x4* O)
{
    constexpr int HB = 32*KT*16;
    constexpr int BO = HB + 16384;
    U4 c;
    f32x4 C0 = toC(*(const float4*)(WB + q*4));
    f32x4 C1 = toC(*(const float4*)(WB + q*4 + 16));
    f32x4 A0[G], A1[G];
    #pragma unroll
    for (int T = 0; T < KT; ++T) {
        c.u = *(const uint4*)(WL + swz(n*(KT*16) + T*16, q));      bf16x8 a0 = c.h;
        c.u = *(const uint4*)(WL + swz((n+16)*(KT*16) + T*16, q)); bf16x8 a1 = c.h;
        #pragma unroll
        for (int g = 0; g < G; ++g) {
            A0[g] = MF(a0, bIn[g*KT+T], (T == 0) ? C0 : A0[g]);
            A1[g] = MF(a1, bIn[g*KT+T], (T == 0) ? C1 : A1[g]);
        }
    }
    // prefetch layer 0/1 weights (depth-2) and layer-0 biases (depth-1)
    c.u = *(const uint4*)(WL + swz(HB + n*16, q));            bf16x8 w0 = c.h;
    c.u = *(const uint4*)(WL + swz(HB + (n+16)*16, q));       bf16x8 w1 = c.h;
    c.u = *(const uint4*)(WL + swz(HB + 512 + n*16, q));      bf16x8 x0 = c.h;
    c.u = *(const uint4*)(WL + swz(HB + 512 + (n+16)*16, q)); bf16x8 x1 = c.h;
    float4 pbl = *(const float4*)(WB + 32 + q*4);
    float4 pbh = *(const float4*)(WB + 32 + q*4 + 16);
    bf16x8 bb[G];
    #pragma unroll
    for (int g = 0; g < G; ++g) bb[g] = transform<LN>(A0[g], A1[g]);
    #pragma unroll 1
    for (int l = 0; l < 32; ++l) {
        const int lp = (l+2 < 32) ? l+2 : 31;
        c.u = *(const uint4*)(WL + swz(HB + lp*512 + n*16, q));      bf16x8 nw0 = c.h;
        c.u = *(const uint4*)(WL + swz(HB + lp*512 + (n+16)*16, q)); bf16x8 nw1 = c.h;
        const int lb_ = (l+1 < 32) ? l+1 : 31;
        float4 nbl = *(const float4*)(WB + 32 + lb_*32 + q*4);
        float4 nbh = *(const float4*)(WB + 32 + lb_*32 + q*4 + 16);
        f32x4 Cl = toC(pbl), Ch = toC(pbh);
        #pragma unroll
        for (int g = 0; g < G; ++g) {
            f32x4 E0 = MF(w0, bb[g], Cl);
            f32x4 E1 = MF(w1, bb[g], Ch);
            bb[g] = transform<LN>(E0, E1);
        }
        w0 = x0; w1 = x1; x0 = nw0; x1 = nw1;
        pbl = nbl; pbh = nbh;
    }
    c.u = *(const uint4*)(WL + swz(BO + n*16, q)); bf16x8 ao = c.h;
    f32x4 Co = toC(*(const float4*)(WB + 1056 + q*4));
    #pragma unroll
    for (int g = 0; g < G; ++g) O[g] = MF(ao, bb[g], Co);
}

// ---------------------------------------------------------------------------
// Weight packing (pi layout) + LN-beta bias folding, one prep kernel.
// ---------------------------------------------------------------------------
__device__ __forceinline__ void pack_body(
    const float* __restrict__ Win, const float* __restrict__ Wh,
    const float* __restrict__ Wout, const float* __restrict__ lng,
    u32* __restrict__ dst, int din, int dout, int KP, int lb, int tid)
{
    int t = lb * 256 + tid;
    int indw = 32*(KP/2);
    int tot = indw + 16384 + 256;
    if (t >= tot) return;
    float lo, hi;
    if (t < indw) {
        int nrow = t / (KP/2), rem = t % (KP/2);
        int T = rem >> 4, d = rem & 15;
        int klo = T*32 + d, khi = klo + 16;
        lo = (klo < din) ? Win[klo*32 + nrow] : 0.f;
        hi = (khi < din) ? Win[khi*32 + nrow] : 0.f;
    } else if (t < indw + 16384) {
        int u = t - indw; int l = u >> 9; int v = u & 511;
        int nrow = v >> 4; int d = v & 15;
        lo = Wh[l*1024 + d*32 + nrow];
        hi = Wh[l*1024 + (d+16)*32 + nrow];
        if (lng) { lo *= lng[l*32 + d]; hi *= lng[l*32 + d + 16]; }
    } else {
        int u = t - indw - 16384; int nrow = u >> 4; int d = u & 15;
        lo = (nrow < dout) ? Wout[d*dout + nrow] : 0.f;
        hi = (nrow < dout) ? Wout[(d+16)*dout + nrow] : 0.f;
        if (lng) { lo *= lng[1024 + d]; hi *= lng[1024 + d + 16]; }
    }
    dst[t] = pk2(lo, hi);
}

__device__ __forceinline__ void fold_body(
    const float* __restrict__ Wh,   const float* __restrict__ bh,
    const float* __restrict__ Wout, const float* __restrict__ bout,
    const float* __restrict__ lnb,  float* __restrict__ fb, int lb, int tid)
{
    int j = lb * 256 + tid;
    if (j < 1024) {
        int l = j >> 5, jj = j & 31;
        float acc = bh[j];
        #pragma unroll
        for (int k = 0; k < 32; ++k)
            acc = fmaf(lnb[l*32 + k], Wh[l*1024 + k*32 + jj], acc);
        fb[j] = acc;
    } else if (j < 1024 + 16) {
        int jj = j - 1024;
        float acc = bout[jj];
        #pragma unroll
        for (int k = 0; k < 32; ++k)
            acc = fmaf(lnb[1024 + k], Wout[k*16 + jj], acc);
        fb[j] = acc;
    }
}

__global__ __launch_bounds__(256) void prep_kernel(
    const float* ne_Win, const float* ne_Wh, const float* ne_Wout,
    const float* ed_Win, const float* ed_Wh, const float* ed_Wout,
    const float* pe_Win, const float* pe_Wh, const float* pe_Wout,
    const float* pe_lng, const float* pe_lnb, const float* pe_bh, const float* pe_bout,
    const float* pv_Win, const float* pv_Wh, const float* pv_Wout,
    const float* pv_lng, const float* pv_lnb, const float* pv_bh, const float* pv_bout,
    const float* de_Win, const float* de_Wh, const float* de_Wout,
    u32* Wne, u32* Wed, u32* Wpe, u32* Wpv, u32* Wde,
    float* Fpe, float* Fpv)
{
    int bx = blockIdx.x, tid = threadIdx.x;
    if      (bx < 70)  pack_body(ne_Win, ne_Wh, ne_Wout, nullptr, Wne,  7, 16, 32, bx,       tid);
    else if (bx < 140) pack_body(ed_Win, ed_Wh, ed_Wout, nullptr, Wed,  5, 16, 32, bx - 70,  tid);
    else if (bx < 210) pack_body(pe_Win, pe_Wh, pe_Wout, pe_lng,  Wpe, 49, 16, 64, bx - 140, tid);
    else if (bx < 280) pack_body(pv_Win, pv_Wh, pv_Wout, pv_lng,  Wpv, 33, 16, 64, bx - 210, tid);
    else if (bx < 350) pack_body(de_Win, de_Wh, de_Wout, nullptr, Wde, 16,  3, 32, bx - 280, tid);
    else if (bx < 355) fold_body(pe_Wh, pe_bh, pe_Wout, pe_bout, pe_lnb, Fpe, bx - 350, tid);
    else               fold_body(pv_Wh, pv_bh, pv_Wout, pv_bout, pv_lnb, Fpv, bx - 355, tid);
}

// ---------------------------------------------------------------------------
// Staging helpers (one element per lane; lanes q>=2 contribute zeros).
// ---------------------------------------------------------------------------
__device__ __forceinline__ bf16x8 stage_node(
    const float* __restrict__ nodes, float g, int e, int q)
{
    uint4 w; w.x = 0u; w.y = 0u; w.z = 0u; w.w = 0u;
    if (q == 0) {
        float2 v01 = *(const float2*)(nodes + (size_t)e*6);
        float2 v23 = *(const float2*)(nodes + (size_t)e*6 + 2);
        w.x = pk2(v01.x, 0.f); w.y = pk2(v01.y, 0.f);
        w.z = pk2(v23.x, 0.f); w.w = pk2(v23.y, 0.f);
    } else if (q == 1) {
        float2 v45 = *(const float2*)(nodes + (size_t)e*6 + 4);
        w.x = pk2(v45.x, 0.f); w.y = pk2(v45.y, 0.f);
        w.z = pk2(g, 0.f);
    }
    U4 c; c.u = w; return c.h;
}

__device__ __forceinline__ bf16x8 stage_edge(
    const float* __restrict__ nodes, const float* __restrict__ edges,
    const int* __restrict__ senders, const int* __restrict__ receivers,
    int e, int b, int q)
{
    uint4 w; w.x = 0u; w.y = 0u; w.z = 0u; w.w = 0u;
    if (q < 2) {
        int s = senders[e], r = receivers[e];
        const float* ps = nodes + ((size_t)b*NN + s)*6;
        const float* pr = nodes + ((size_t)b*NN + r)*6;
        float2 s01 = *(const float2*)ps; float s2v = ps[2];
        float2 r01 = *(const float2*)pr; float r2v = pr[2];
        float r0 = s01.x - r01.x, r1 = s01.y - r01.y, r2 = s2v - r2v;
        if (q == 0) {
            w.x = pk2(edges[e], 0.f); w.y = pk2(r0, 0.f);
            w.z = pk2(r1, 0.f);       w.w = pk2(r2, 0.f);
        } else {
            w.x = pk2(sqrtf(r0*r0 + r1*r1 + r2*r2), 0.f);
        }
    }
    U4 c; c.u = w; return c.h;
}

#define WAVE_SETUP \
    const int lane = threadIdx.x & 63; \
    const int wid  = threadIdx.x >> 6; \
    const int n = lane & 15, q = lane >> 4; \
    (void)lane;

// ---------------------------------------------------------------------------
// encode: 512-thr blocks (8 waves), G=2 (32 elems/wave), 512 blocks.
// ---------------------------------------------------------------------------
__global__ __launch_bounds__(512, 4) void encode_kernel(
    const float* __restrict__ nodes, const float* __restrict__ edges,
    const float* __restrict__ gvec,
    const int* __restrict__ senders, const int* __restrict__ receivers,
    const u32* __restrict__ Wne, const float* __restrict__ ne_bin,
    const float* __restrict__ ne_bh, const float* __restrict__ ne_bout,
    const u32* __restrict__ Wed, const float* __restrict__ ed_bin,
    const float* __restrict__ ed_bh, const float* __restrict__ ed_bout,
    float* __restrict__ ve, float* __restrict__ ee)
{
    __shared__ __align__(16) u32 SL[17152 + 1072];
    u32* WL = SL;
    float* WB = (float*)(SL + 17152);
    WAVE_SETUP
    const bool edge_stage = blockIdx.x >= 256;
    stage_weights(WL, WB,
                  edge_stage ? Wed : Wne,
                  edge_stage ? ed_bin : ne_bin,
                  edge_stage ? ed_bh : ne_bh,
                  edge_stage ? ed_bout : ne_bout,
                  17152, 16, threadIdx.x, 512);
    __syncthreads();
    const int lb = edge_stage ? (blockIdx.x - 256) : blockIdx.x;
    const int e0 = (lb*8 + wid) * 32;
    const int eA = e0 + n, eB = e0 + 16 + n;
    const int bA = eA >> 15, bB = eB >> 15;
    bf16x8 a[2];
    if (!edge_stage) {
        a[0] = stage_node(nodes, gvec[bA], eA, q);
        a[1] = stage_node(nodes, gvec[bB], eB, q);
    } else {
        a[0] = stage_edge(nodes, edges, senders, receivers, eA, bA, q);
        a[1] = stage_edge(nodes, edges, senders, receivers, eB, bB, q);
    }
    float* dst = edge_stage ? ee : ve;
    f32x4 O[2];
    mlp_core<1, 2, false>(a, WL, WB, n, q, O);
    float4 st;
    st.x = fmaxf(O[0][0], 0.f); st.y = fmaxf(O[0][1], 0.f);
    st.z = fmaxf(O[0][2], 0.f); st.w = fmaxf(O[0][3], 0.f);
    *(float4*)(dst + (size_t)eA*16 + q*4) = st;
    st.x = fmaxf(O[1][0], 0.f); st.y = fmaxf(O[1][1], 0.f);
    st.z = fmaxf(O[1][2], 0.f); st.w = fmaxf(O[1][3], 0.f);
    *(float4*)(dst + (size_t)eB*16 + q*4) = st;
}

// ---------------------------------------------------------------------------
// edge_update: 256-thr blocks (4 waves), G=4 (64 elems/wave), 256 blocks.
// ---------------------------------------------------------------------------
__global__ __launch_bounds__(256, 1) void edge_update_kernel(
    const float* __restrict__ gvec,
    const int* __restrict__ senders, const int* __restrict__ receivers,
    const float* __restrict__ ve, float* __restrict__ ee, float* __restrict__ agg,
    const u32* __restrict__ Wp, const float* __restrict__ bin,
    const float* __restrict__ fb)
{
    __shared__ __align__(16) u32 SL[17664 + 1072 + 4*320];
    u32* WL = SL;
    float* WB = (float*)(SL + 17664);
    WAVE_SETUP
    float* X = (float*)(SL + 18736) + wid*320;
    stage_weights(WL, WB, Wp, bin, fb, fb + 1024, 17664, 16, threadIdx.x, 256);
    __syncthreads();
    const int e0 = (blockIdx.x*4 + wid) * 64;
    bf16x8 a[8];
    int rsv[4];
    #pragma unroll
    for (int g = 0; g < 4; ++g) {
        const int e = e0 + 16*g + n;
        const int b = e >> 15;
        const int s = senders[e], r = receivers[e];
        rsv[g] = r;
        float4 eev = *(const float4*)(ee + (size_t)e*16 + q*4);
        float4 vsv = *(const float4*)(ve + ((size_t)b*NN + s)*16 + q*4);
        float4 vrv = *(const float4*)(ve + ((size_t)b*NN + r)*16 + q*4);
        float gg = gvec[b];
        U4 c;
        c.u.x = pk2(eev.x, vsv.x); c.u.y = pk2(eev.y, vsv.y);
        c.u.z = pk2(eev.z, vsv.z); c.u.w = pk2(eev.w, vsv.w);
        a[g*2+0] = c.h;
        c.u.x = pk2(vrv.x, (q == 0) ? gg : 0.f);
        c.u.y = pk2(vrv.y, 0.f); c.u.z = pk2(vrv.z, 0.f); c.u.w = pk2(vrv.w, 0.f);
        a[g*2+1] = c.h;
    }
    f32x4 O[4];
    mlp_core<2, 4, true>(a, WL, WB, n, q, O);
    #pragma unroll
    for (int g = 0; g < 4; ++g) {
        const int e = e0 + 16*g + n;
        float4 st;
        st.x = fmaxf(O[g][0], 0.f); st.y = fmaxf(O[g][1], 0.f);
        st.z = fmaxf(O[g][2], 0.f); st.w = fmaxf(O[g][3], 0.f);
        *(float4*)(ee + (size_t)e*16 + q*4) = st;
        // Coalesced atomics: wave-private LDS transpose so one atomic
        // instruction hits 4 receiver lines (16 lanes share a receiver).
        *(float4*)(X + n*20 + q*4) = st;
        #pragma unroll
        for (int rr = 0; rr < 4; ++rr) {
            int em = e0 + 16*g + q*4 + rr;
            float v = X[(q*4+rr)*20 + n];
            int rc = __shfl(rsv[g], q*4 + rr);
            atomicAdd(agg + ((size_t)(em >> 15)*NN + rc)*16 + n, v);
        }
    }
}

// ---------------------------------------------------------------------------
// node_update: 256-thr blocks (4 waves), G=4, 256 blocks.
// DEC=true (message-passing step 2): fuses the decode MLP — the pv output
// C-layout IS decode's input B-layout lane-for-lane (zero transpose, no ve
// round-trip); writes d_out directly, skips the ve store.
// ---------------------------------------------------------------------------
template<bool DEC>
__global__ __launch_bounds__(256, 1) void node_update_kernel(
    const float* __restrict__ gvec,
    const float* __restrict__ agg, float* __restrict__ ve,
    const u32* __restrict__ Wp, const float* __restrict__ bin,
    const float* __restrict__ fb,
    const u32* __restrict__ Wde, const float* __restrict__ de_bin,
    const float* __restrict__ de_bh, const float* __restrict__ de_bout,
    float* __restrict__ out)
{
    __shared__ __align__(16) u32 SL[DEC ? 36960 : 18736];
    u32* WL = SL;
    float* WB = (float*)(SL + 17664);
    u32* WL2 = SL + 18736;
    float* WB2 = (float*)(SL + 35888);
    WAVE_SETUP
    stage_weights(WL, WB, Wp, bin, fb, fb + 1024, 17664, 16, threadIdx.x, 256);
    if (DEC)
        stage_weights(WL2, WB2, Wde, de_bin, de_bh, de_bout, 17152, 3, threadIdx.x, 256);
    __syncthreads();
    const int e0 = (blockIdx.x*4 + wid) * 64;
    bf16x8 a[8];
    #pragma unroll
    for (int g = 0; g < 4; ++g) {
        const int e = e0 + 16*g + n;
        const int b = e >> 15;
        float4 agv = *(const float4*)(agg + (size_t)e*16 + q*4);
        float4 vev = *(const float4*)(ve  + (size_t)e*16 + q*4);
        float gg = gvec[b];
        U4 c;
        c.u.x = pk2(agv.x, vev.x); c.u.y = pk2(agv.y, vev.y);
        c.u.z = pk2(agv.z, vev.z); c.u.w = pk2(agv.w, vev.w);
        a[g*2+0] = c.h;
        c.u.x = (q == 0) ? pk2(gg, 0.f) : 0u;
        c.u.y = 0u; c.u.z = 0u; c.u.w = 0u;
        a[g*2+1] = c.h;
    }
    f32x4 O[4];
    mlp_core<2, 4, true>(a, WL, WB, n, q, O);
    if (!DEC) {
        #pragma unroll
        for (int g = 0; g < 4; ++g) {
            const int e = e0 + 16*g + n;
            float4 st;
            st.x = fmaxf(O[g][0], 0.f); st.y = fmaxf(O[g][1], 0.f);
            st.z = fmaxf(O[g][2], 0.f); st.w = fmaxf(O[g][3], 0.f);
            *(float4*)(ve + (size_t)e*16 + q*4) = st;
        }
    } else {
        bf16x8 aD[4];
        #pragma unroll
        for (int g = 0; g < 4; ++g) {
            U4 c;
            c.u.x = pk2(fmaxf(O[g][0], 0.f), 0.f);
            c.u.y = pk2(fmaxf(O[g][1], 0.f), 0.f);
            c.u.z = pk2(fmaxf(O[g][2], 0.f), 0.f);
            c.u.w = pk2(fmaxf(O[g][3], 0.f), 0.f);
            aD[g] = c.h;
        }
        f32x4 OD[4];
        mlp_core<1, 4, false>(aD, WL2, WB2, n, q, OD);
        if (q == 0) {
            #pragma unroll
            for (int g = 0; g < 4; ++g) {
                const int e = e0 + 16*g + n;
                out[(size_t)e*3 + 0] = fmaxf(OD[g][0], 0.f);
                out[(size_t)e*3 + 1] = fmaxf(OD[g][1], 0.f);
                out[(size_t)e*3 + 2] = fmaxf(OD[g][2], 0.f);
            }
        }
    }
}

// ---------------------------------------------------------------------------
// launch
// ---------------------------------------------------------------------------
extern "C" void kernel_launch(void* const* d_in, const int* in_sizes, int n_in,
                              void* d_out, int out_size, void* d_ws, size_t ws_size,
                              hipStream_t stream)
{
    const float* nodes     = (const float*)d_in[0];
    const float* edges     = (const float*)d_in[1];
    const float* gvec      = (const float*)d_in[2];
    const int*   senders   = (const int*)  d_in[3];
    const int*   receivers = (const int*)  d_in[4];

    const float* ne_Win  = (const float*)d_in[5];
    const float* ne_bin  = (const float*)d_in[6];
    const float* ne_Wh   = (const float*)d_in[7];
    const float* ne_bh   = (const float*)d_in[8];
    const float* ne_Wout = (const float*)d_in[9];
    const float* ne_bout = (const float*)d_in[10];

    const float* ed_Win  = (const float*)d_in[11];
    const float* ed_bin  = (const float*)d_in[12];
    const float* ed_Wh   = (const float*)d_in[13];
    const float* ed_bh   = (const float*)d_in[14];
    const float* ed_Wout = (const float*)d_in[15];
    const float* ed_bout = (const float*)d_in[16];

    const float* pe_Win  = (const float*)d_in[17];
    const float* pe_bin  = (const float*)d_in[18];
    const float* pe_Wh   = (const float*)d_in[19];
    const float* pe_bh   = (const float*)d_in[20];
    const float* pe_Wout = (const float*)d_in[21];
    const float* pe_bout = (const float*)d_in[22];
    const float* pe_lng  = (const float*)d_in[23];
    const float* pe_lnb  = (const float*)d_in[24];

    const float* pv_Win  = (const float*)d_in[25];
    const float* pv_bin  = (const float*)d_in[26];
    const float* pv_Wh   = (const float*)d_in[27];
    const float* pv_bh   = (const float*)d_in[28];
    const float* pv_Wout = (const float*)d_in[29];
    const float* pv_bout = (const float*)d_in[30];
    const float* pv_lng  = (const float*)d_in[31];
    const float* pv_lnb  = (const float*)d_in[32];

    const float* de_Win  = (const float*)d_in[33];
    const float* de_bin  = (const float*)d_in[34];
    const float* de_Wh   = (const float*)d_in[35];
    const float* de_bh   = (const float*)d_in[36];
    const float* de_Wout = (const float*)d_in[37];
    const float* de_bout = (const float*)d_in[38];

    // workspace: ve | ee | agg (4 MB each) | packed bf16 weights | folded biases
    float* ve  = (float*)d_ws;
    float* ee  = ve + (size_t)1048576;
    float* agg = ee + (size_t)1048576;
    u32* Wne = (u32*)(agg + (size_t)1048576);
    u32* Wed = Wne + 17152;
    u32* Wpe = Wed + 17152;
    u32* Wpv = Wpe + 17664;
    u32* Wde = Wpv + 17664;
    float* Fpe = (float*)(Wde + 17152);
    float* Fpv = Fpe + 1040;

    prep_kernel<<<360, dim3(256), 0, stream>>>(
        ne_Win, ne_Wh, ne_Wout,
        ed_Win, ed_Wh, ed_Wout,
        pe_Win, pe_Wh, pe_Wout, pe_lng, pe_lnb, pe_bh, pe_bout,
        pv_Win, pv_Wh, pv_Wout, pv_lng, pv_lnb, pv_bh, pv_bout,
        de_Win, de_Wh, de_Wout,
        Wne, Wed, Wpe, Wpv, Wde, Fpe, Fpv);

    encode_kernel<<<512, dim3(512), 0, stream>>>(nodes, edges, gvec, senders, receivers,
        Wne, ne_bin, ne_bh, ne_bout,
        Wed, ed_bin, ed_bh, ed_bout, ve, ee);

    for (int step = 0; step < 2; ++step) {
        hipMemsetAsync(agg, 0, (size_t)BB * NN * 16 * sizeof(float), stream);
        edge_update_kernel<<<256, dim3(256), 0, stream>>>(gvec, senders, receivers,
            ve, ee, agg, Wpe, pe_bin, Fpe);
        if (step == 0) {
            node_update_kernel<false><<<256, dim3(256), 0, stream>>>(gvec, agg, ve,
                Wpv, pv_bin, Fpv, Wde, de_bin, de_bh, de_bout, (float*)d_out);
        } else {
            node_update_kernel<true><<<256, dim3(256), 0, stream>>>(gvec, agg, ve,
                Wpv, pv_bin, Fpv, Wde, de_bin, de_bh, de_bout, (float*)d_out);
        }
    }
}

// Round 12
// 303.669 us; speedup vs baseline: 1.1396x; 1.1396x over previous
//
#include <hip/hip_runtime.h>

#define BB 2
#define NN 32768
#define EN 32768

typedef unsigned int u32;
typedef __attribute__((ext_vector_type(8))) short bf16x8;
typedef __attribute__((ext_vector_type(4))) float f32x4;
typedef __attribute__((ext_vector_type(2))) float f32x2;

union U4 { uint4 u; bf16x8 h; };

#if defined(__has_builtin)
#if __has_builtin(__builtin_amdgcn_cvt_pk_bf16_f32)
#define HAVE_CVT_PK 1
#endif
#endif

#ifdef HAVE_CVT_PK
typedef __attribute__((ext_vector_type(2))) __bf16 bfv2;
__device__ __forceinline__ u32 pk2(float lo, float hi) {
    bfv2 v = __builtin_amdgcn_cvt_pk_bf16_f32(lo, hi);
    return __builtin_bit_cast(u32, v);
}
#else
__device__ __forceinline__ u32 pk2(float lo, float hi) {
    u32 a = __builtin_bit_cast(u32, lo);
    u32 b = __builtin_bit_cast(u32, hi);
    a += 0x7FFFu + ((a >> 16) & 1u);
    b += 0x7FFFu + ((b >> 16) & 1u);
    return (a >> 16) | (b & 0xFFFF0000u);
}
#endif

__device__ __forceinline__ f32x4 MF(bf16x8 a, bf16x8 b, f32x4 c) {
    return __builtin_amdgcn_mfma_f32_16x16x32_bf16(a, b, c, 0, 0, 0);
}
__device__ __forceinline__ f32x4 toC(float4 v) {
    f32x4 r = {v.x, v.y, v.z, v.w};
    return r;
}

// LDS weight swizzle (4-way residual conflict; floor for 16-dword rows).
__device__ __forceinline__ int swz(int rowbase, int q) {
    return rowbase + (((q + (rowbase >> 5)) & 3) << 2);
}

// ---------------------------------------------------------------------------
// Layer epilogue. Bias already in D (MFMA C operand). LN = normalize-only
// (affine folded into weights at pack time). (lo,hi) feature pairs live in
// f32x2 vectors -> v_pk_max/v_pk_fma dual-f32 ops (halves epilogue VALU).
// LN stats across lanes (n, q=0..3): 3 PARALLEL shfl_xor (16/32/48).
// ---------------------------------------------------------------------------
template<bool LN>
__device__ __forceinline__ bf16x8 transform(f32x4 D0, f32x4 D1)
{
    f32x2 p0 = {D0[0], D1[0]}, p1 = {D0[1], D1[1]};
    f32x2 p2 = {D0[2], D1[2]}, p3 = {D0[3], D1[3]};
    const f32x2 zz = {0.f, 0.f};
    p0 = __builtin_elementwise_max(p0, zz);
    p1 = __builtin_elementwise_max(p1, zz);
    p2 = __builtin_elementwise_max(p2, zz);
    p3 = __builtin_elementwise_max(p3, zz);
    if (LN) {
        f32x2 sv = (p0 + p1) + (p2 + p3);
        f32x2 tv = __builtin_elementwise_fma(p0, p0,
                   __builtin_elementwise_fma(p1, p1,
                   __builtin_elementwise_fma(p2, p2, p3 * p3)));
        float s = sv.x + sv.y;
        float t = tv.x + tv.y;
        float sa = __shfl_xor(s, 16), sb = __shfl_xor(s, 32), sc = __shfl_xor(s, 48);
        float ta = __shfl_xor(t, 16), tb = __shfl_xor(t, 32), tc = __shfl_xor(t, 48);
        s = (s + sa) + (sb + sc);
        t = (t + ta) + (tb + tc);
        float mu  = s * (1.f/32.f);
        float var = fmaf(-mu, mu, t * (1.f/32.f));
        float rs  = rsqrtf(var + 1e-5f);
        float nt  = -mu * rs;
        f32x2 rs2 = {rs, rs}, nt2 = {nt, nt};
        p0 = __builtin_elementwise_fma(p0, rs2, nt2);
        p1 = __builtin_elementwise_fma(p1, rs2, nt2);
        p2 = __builtin_elementwise_fma(p2, rs2, nt2);
        p3 = __builtin_elementwise_fma(p3, rs2, nt2);
    }
    U4 c;
    c.u.x = pk2(p0.x, p0.y); c.u.y = pk2(p1.x, p1.y);
    c.u.z = pk2(p2.x, p2.y); c.u.w = pk2(p3.x, p3.y);
    return c.h;
}

// ---------------------------------------------------------------------------
// Block-level staging of packed weights + biases into LDS (swizzled).
// WB layout (floats): [0..32) bin | [32..1056) hidden biases | [1056..1072) out
// ---------------------------------------------------------------------------
__device__ __forceinline__ void stage_weights(
    u32* WL, float* WB, const u32* __restrict__ Wp,
    const float* __restrict__ bin, const float* __restrict__ bhid,
    const float* __restrict__ bo, int wtot, int nbo, int tid, int nthr)
{
    for (int C = tid; C * 4 < wtot; C += nthr) {
        int Cp = (C & ~3) | ((C + (C >> 3)) & 3);
        *(uint4*)(WL + Cp*4) = *(const uint4*)(Wp + C*4);
    }
    for (int i = tid; i < 1072; i += nthr) {
        float v;
        if (i < 32)         v = bin[i];
        else if (i < 1056)  v = bhid[i-32];
        else                v = (i-1056 < nbo) ? bo[i-1056] : 0.f;
        WB[i] = v;
    }
    __syncthreads();
}

// ---------------------------------------------------------------------------
// Wave-level deep MLP over TWO independent 16-element groups; weights/biases
// from LDS. Biases enter via the MFMA C operand (free adds). Depth-2 weight
// prefetch + depth-1 bias prefetch. O* = final MFMA D (bias incl, pre-relu).
// WL (pi layout): [Bin 32 x KT*16 dw][Bh 32 x 512 dw][Bo 256 dw]
// bIn: group g's input B-frags at bIn[g*KT + T].
// ---------------------------------------------------------------------------
template<int KT, bool LN>
__device__ __forceinline__ void mlp_core2(
    const bf16x8* bIn, const u32* WL, const float* WB,
    int n, int q, f32x4& OA, f32x4& OB)
{
    constexpr int HB = 32*KT*16;
    constexpr int BO = HB + 16384;
    U4 c;
    f32x4 C0 = toC(*(const float4*)(WB + q*4));
    f32x4 C1 = toC(*(const float4*)(WB + q*4 + 16));
    f32x4 A0, A1, B0, B1;
    #pragma unroll
    for (int T = 0; T < KT; ++T) {
        c.u = *(const uint4*)(WL + swz(n*(KT*16) + T*16, q));      bf16x8 a0 = c.h;
        c.u = *(const uint4*)(WL + swz((n+16)*(KT*16) + T*16, q)); bf16x8 a1 = c.h;
        A0 = MF(a0, bIn[T],    (T == 0) ? C0 : A0);
        A1 = MF(a1, bIn[T],    (T == 0) ? C1 : A1);
        B0 = MF(a0, bIn[KT+T], (T == 0) ? C0 : B0);
        B1 = MF(a1, bIn[KT+T], (T == 0) ? C1 : B1);
    }
    // prefetch layer 0/1 weights (depth-2) and layer-0 biases (depth-1)
    c.u = *(const uint4*)(WL + swz(HB + n*16, q));            bf16x8 w0 = c.h;
    c.u = *(const uint4*)(WL + swz(HB + (n+16)*16, q));       bf16x8 w1 = c.h;
    c.u = *(const uint4*)(WL + swz(HB + 512 + n*16, q));      bf16x8 x0 = c.h;
    c.u = *(const uint4*)(WL + swz(HB + 512 + (n+16)*16, q)); bf16x8 x1 = c.h;
    float4 pbl = *(const float4*)(WB + 32 + q*4);
    float4 pbh = *(const float4*)(WB + 32 + q*4 + 16);
    bf16x8 bb0 = transform<LN>(A0, A1);
    bf16x8 bb1 = transform<LN>(B0, B1);
    #pragma unroll 1
    for (int l = 0; l < 32; ++l) {
        const int lp = (l+2 < 32) ? l+2 : 31;
        c.u = *(const uint4*)(WL + swz(HB + lp*512 + n*16, q));      bf16x8 nw0 = c.h;
        c.u = *(const uint4*)(WL + swz(HB + lp*512 + (n+16)*16, q)); bf16x8 nw1 = c.h;
        const int lb_ = (l+1 < 32) ? l+1 : 31;
        float4 nbl = *(const float4*)(WB + 32 + lb_*32 + q*4);
        float4 nbh = *(const float4*)(WB + 32 + lb_*32 + q*4 + 16);
        f32x4 Cl = toC(pbl), Ch = toC(pbh);
        f32x4 E0 = MF(w0, bb0, Cl);
        f32x4 E1 = MF(w1, bb0, Ch);
        f32x4 F0 = MF(w0, bb1, Cl);
        f32x4 F1 = MF(w1, bb1, Ch);
        bb0 = transform<LN>(E0, E1);
        bb1 = transform<LN>(F0, F1);
        w0 = x0; w1 = x1; x0 = nw0; x1 = nw1;
        pbl = nbl; pbh = nbh;
    }
    c.u = *(const uint4*)(WL + swz(BO + n*16, q)); bf16x8 ao = c.h;
    f32x4 Co = toC(*(const float4*)(WB + 1056 + q*4));
    OA = MF(ao, bb0, Co);
    OB = MF(ao, bb1, Co);
}

// ---------------------------------------------------------------------------
// Weight packing (pi layout) + LN-beta bias folding, one prep kernel.
// ---------------------------------------------------------------------------
__device__ __forceinline__ void pack_body(
    const float* __restrict__ Win, const float* __restrict__ Wh,
    const float* __restrict__ Wout, const float* __restrict__ lng,
    u32* __restrict__ dst, int din, int dout, int KP, int lb, int tid)
{
    int t = lb * 256 + tid;
    int indw = 32*(KP/2);
    int tot = indw + 16384 + 256;
    if (t >= tot) return;
    float lo, hi;
    if (t < indw) {
        int nrow = t / (KP/2), rem = t % (KP/2);
        int T = rem >> 4, d = rem & 15;
        int klo = T*32 + d, khi = klo + 16;
        lo = (klo < din) ? Win[klo*32 + nrow] : 0.f;
        hi = (khi < din) ? Win[khi*32 + nrow] : 0.f;
    } else if (t < indw + 16384) {
        int u = t - indw; int l = u >> 9; int v = u & 511;
        int nrow = v >> 4; int d = v & 15;
        lo = Wh[l*1024 + d*32 + nrow];
        hi = Wh[l*1024 + (d+16)*32 + nrow];
        if (lng) { lo *= lng[l*32 + d]; hi *= lng[l*32 + d + 16]; }
    } else {
        int u = t - indw - 16384; int nrow = u >> 4; int d = u & 15;
        lo = (nrow < dout) ? Wout[d*dout + nrow] : 0.f;
        hi = (nrow < dout) ? Wout[(d+16)*dout + nrow] : 0.f;
        if (lng) { lo *= lng[1024 + d]; hi *= lng[1024 + d + 16]; }
    }
    dst[t] = pk2(lo, hi);
}

__device__ __forceinline__ void fold_body(
    const float* __restrict__ Wh,   const float* __restrict__ bh,
    const float* __restrict__ Wout, const float* __restrict__ bout,
    const float* __restrict__ lnb,  float* __restrict__ fb, int lb, int tid)
{
    int j = lb * 256 + tid;
    if (j < 1024) {
        int l = j >> 5, jj = j & 31;
        float acc = bh[j];
        #pragma unroll
        for (int k = 0; k < 32; ++k)
            acc = fmaf(lnb[l*32 + k], Wh[l*1024 + k*32 + jj], acc);
        fb[j] = acc;
    } else if (j < 1024 + 16) {
        int jj = j - 1024;
        float acc = bout[jj];
        #pragma unroll
        for (int k = 0; k < 32; ++k)
            acc = fmaf(lnb[1024 + k], Wout[k*16 + jj], acc);
        fb[j] = acc;
    }
}

__global__ __launch_bounds__(256) void prep_kernel(
    const float* ne_Win, const float* ne_Wh, const float* ne_Wout,
    const float* ed_Win, const float* ed_Wh, const float* ed_Wout,
    const float* pe_Win, const float* pe_Wh, const float* pe_Wout,
    const float* pe_lng, const float* pe_lnb, const float* pe_bh, const float* pe_bout,
    const float* pv_Win, const float* pv_Wh, const float* pv_Wout,
    const float* pv_lng, const float* pv_lnb, const float* pv_bh, const float* pv_bout,
    const float* de_Win, const float* de_Wh, const float* de_Wout,
    u32* Wne, u32* Wed, u32* Wpe, u32* Wpv, u32* Wde,
    float* Fpe, float* Fpv)
{
    int bx = blockIdx.x, tid = threadIdx.x;
    if      (bx < 70)  pack_body(ne_Win, ne_Wh, ne_Wout, nullptr, Wne,  7, 16, 32, bx,       tid);
    else if (bx < 140) pack_body(ed_Win, ed_Wh, ed_Wout, nullptr, Wed,  5, 16, 32, bx - 70,  tid);
    else if (bx < 210) pack_body(pe_Win, pe_Wh, pe_Wout, pe_lng,  Wpe, 49, 16, 64, bx - 140, tid);
    else if (bx < 280) pack_body(pv_Win, pv_Wh, pv_Wout, pv_lng,  Wpv, 33, 16, 64, bx - 210, tid);
    else if (bx < 350) pack_body(de_Win, de_Wh, de_Wout, nullptr, Wde, 16,  3, 32, bx - 280, tid);
    else if (bx < 355) fold_body(pe_Wh, pe_bh, pe_Wout, pe_bout, pe_lnb, Fpe, bx - 350, tid);
    else               fold_body(pv_Wh, pv_bh, pv_Wout, pv_bout, pv_lnb, Fpv, bx - 355, tid);
}

// ---------------------------------------------------------------------------
// Staging helpers (one element per lane; lanes q>=2 contribute zeros).
// ---------------------------------------------------------------------------
__device__ __forceinline__ bf16x8 stage_node(
    const float* __restrict__ nodes, float g, int e, int q)
{
    uint4 w; w.x = 0u; w.y = 0u; w.z = 0u; w.w = 0u;
    if (q == 0) {
        float2 v01 = *(const float2*)(nodes + (size_t)e*6);
        float2 v23 = *(const float2*)(nodes + (size_t)e*6 + 2);
        w.x = pk2(v01.x, 0.f); w.y = pk2(v01.y, 0.f);
        w.z = pk2(v23.x, 0.f); w.w = pk2(v23.y, 0.f);
    } else if (q == 1) {
        float2 v45 = *(const float2*)(nodes + (size_t)e*6 + 4);
        w.x = pk2(v45.x, 0.f); w.y = pk2(v45.y, 0.f);
        w.z = pk2(g, 0.f);
    }
    U4 c; c.u = w; return c.h;
}

__device__ __forceinline__ bf16x8 stage_edge(
    const float* __restrict__ nodes, const float* __restrict__ edges,
    const int* __restrict__ senders, const int* __restrict__ receivers,
    int e, int b, int q)
{
    uint4 w; w.x = 0u; w.y = 0u; w.z = 0u; w.w = 0u;
    if (q < 2) {
        int s = senders[e], r = receivers[e];
        const float* ps = nodes + ((size_t)b*NN + s)*6;
        const float* pr = nodes + ((size_t)b*NN + r)*6;
        float2 s01 = *(const float2*)ps; float s2v = ps[2];
        float2 r01 = *(const float2*)pr; float r2v = pr[2];
        float r0 = s01.x - r01.x, r1 = s01.y - r01.y, r2 = s2v - r2v;
        if (q == 0) {
            w.x = pk2(edges[e], 0.f); w.y = pk2(r0, 0.f);
            w.z = pk2(r1, 0.f);       w.w = pk2(r2, 0.f);
        } else {
            w.x = pk2(sqrtf(r0*r0 + r1*r1 + r2*r2), 0.f);
        }
    }
    U4 c; c.u = w; return c.h;
}

#define WAVE_SETUP \
    const int lane = threadIdx.x & 63; \
    const int wid  = threadIdx.x >> 6; \
    const int n = lane & 15, q = lane >> 4; \
    (void)lane;

// ---------------------------------------------------------------------------
// encode: 512-thr blocks (8 waves), 2 groups/wave, 512 blocks (2 blocks/CU).
// ---------------------------------------------------------------------------
__global__ __launch_bounds__(512, 4) void encode_kernel(
    const float* __restrict__ nodes, const float* __restrict__ edges,
    const float* __restrict__ gvec,
    const int* __restrict__ senders, const int* __restrict__ receivers,
    const u32* __restrict__ Wne, const float* __restrict__ ne_bin,
    const float* __restrict__ ne_bh, const float* __restrict__ ne_bout,
    const u32* __restrict__ Wed, const float* __restrict__ ed_bin,
    const float* __restrict__ ed_bh, const float* __restrict__ ed_bout,
    float* __restrict__ ve, float* __restrict__ ee)
{
    __shared__ __align__(16) u32 SL[17152 + 1072];
    u32* WL = SL;
    float* WB = (float*)(SL + 17152);
    WAVE_SETUP
    const bool edge_stage = blockIdx.x >= 256;
    stage_weights(WL, WB,
                  edge_stage ? Wed : Wne,
                  edge_stage ? ed_bin : ne_bin,
                  edge_stage ? ed_bh : ne_bh,
                  edge_stage ? ed_bout : ne_bout,
                  17152, 16, threadIdx.x, 512);
    const int lb = edge_stage ? (blockIdx.x - 256) : blockIdx.x;
    const int e0 = (lb*8 + wid) * 32;
    const int eA = e0 + n, eB = e0 + 16 + n;
    const int bA = eA >> 15, bB = eB >> 15;
    bf16x8 a[2];
    if (!edge_stage) {
        a[0] = stage_node(nodes, gvec[bA], eA, q);
        a[1] = stage_node(nodes, gvec[bB], eB, q);
    } else {
        a[0] = stage_edge(nodes, edges, senders, receivers, eA, bA, q);
        a[1] = stage_edge(nodes, edges, senders, receivers, eB, bB, q);
    }
    float* dst = edge_stage ? ee : ve;
    f32x4 OA, OB;
    mlp_core2<1, false>(a, WL, WB, n, q, OA, OB);
    float4 st;
    st.x = fmaxf(OA[0], 0.f); st.y = fmaxf(OA[1], 0.f);
    st.z = fmaxf(OA[2], 0.f); st.w = fmaxf(OA[3], 0.f);
    *(float4*)(dst + (size_t)eA*16 + q*4) = st;
    st.x = fmaxf(OB[0], 0.f); st.y = fmaxf(OB[1], 0.f);
    st.z = fmaxf(OB[2], 0.f); st.w = fmaxf(OB[3], 0.f);
    *(float4*)(dst + (size_t)eB*16 + q*4) = st;
}

// ---------------------------------------------------------------------------
// edge_update: 512-thr blocks (8 waves), 2 groups/wave, 256 blocks.
// ---------------------------------------------------------------------------
__global__ __launch_bounds__(512, 2) void edge_update_kernel(
    const float* __restrict__ gvec,
    const int* __restrict__ senders, const int* __restrict__ receivers,
    const float* __restrict__ ve, float* __restrict__ ee, float* __restrict__ agg,
    const u32* __restrict__ Wp, const float* __restrict__ bin,
    const float* __restrict__ fb)
{
    __shared__ __align__(16) u32 SL[17664 + 1072 + 8*320];
    u32* WL = SL;
    float* WB = (float*)(SL + 17664);
    WAVE_SETUP
    float* X = (float*)(SL + 18736) + wid*320;
    stage_weights(WL, WB, Wp, bin, fb, fb + 1024, 17664, 16, threadIdx.x, 512);
    const int e0 = (blockIdx.x*8 + wid) * 32;
    const int eA = e0 + n, eB = e0 + 16 + n;
    const int bA = eA >> 15, bB = eB >> 15;
    const int sA = senders[eA], rA = receivers[eA];
    const int sB = senders[eB], rB = receivers[eB];
    float gA = gvec[bA], gB = gvec[bB];
    bf16x8 a[4];
    {
        float4 eev = *(const float4*)(ee + (size_t)eA*16 + q*4);
        float4 vsv = *(const float4*)(ve + ((size_t)bA*NN + sA)*16 + q*4);
        float4 vrv = *(const float4*)(ve + ((size_t)bA*NN + rA)*16 + q*4);
        U4 c;
        c.u.x = pk2(eev.x, vsv.x); c.u.y = pk2(eev.y, vsv.y);
        c.u.z = pk2(eev.z, vsv.z); c.u.w = pk2(eev.w, vsv.w);
        a[0] = c.h;
        c.u.x = pk2(vrv.x, (q == 0) ? gA : 0.f);
        c.u.y = pk2(vrv.y, 0.f); c.u.z = pk2(vrv.z, 0.f); c.u.w = pk2(vrv.w, 0.f);
        a[1] = c.h;
    }
    {
        float4 eev = *(const float4*)(ee + (size_t)eB*16 + q*4);
        float4 vsv = *(const float4*)(ve + ((size_t)bB*NN + sB)*16 + q*4);
        float4 vrv = *(const float4*)(ve + ((size_t)bB*NN + rB)*16 + q*4);
        U4 c;
        c.u.x = pk2(eev.x, vsv.x); c.u.y = pk2(eev.y, vsv.y);
        c.u.z = pk2(eev.z, vsv.z); c.u.w = pk2(eev.w, vsv.w);
        a[2] = c.h;
        c.u.x = pk2(vrv.x, (q == 0) ? gB : 0.f);
        c.u.y = pk2(vrv.y, 0.f); c.u.z = pk2(vrv.z, 0.f); c.u.w = pk2(vrv.w, 0.f);
        a[3] = c.h;
    }
    f32x4 OA, OB;
    mlp_core2<2, true>(a, WL, WB, n, q, OA, OB);
    float4 stA, stB;
    stA.x = fmaxf(OA[0], 0.f); stA.y = fmaxf(OA[1], 0.f);
    stA.z = fmaxf(OA[2], 0.f); stA.w = fmaxf(OA[3], 0.f);
    stB.x = fmaxf(OB[0], 0.f); stB.y = fmaxf(OB[1], 0.f);
    stB.z = fmaxf(OB[2], 0.f); stB.w = fmaxf(OB[3], 0.f);
    *(float4*)(ee + (size_t)eA*16 + q*4) = stA;
    *(float4*)(ee + (size_t)eB*16 + q*4) = stB;
    // Coalesced atomics: wave-private LDS transpose so one atomic instruction
    // hits 4 receiver lines (16 lanes share a receiver).
    *(float4*)(X + n*20 + q*4) = stA;
    #pragma unroll
    for (int rr = 0; rr < 4; ++rr) {
        int em = e0 + q*4 + rr;
        float v = X[(q*4+rr)*20 + n];
        int rc = __shfl(rA, q*4 + rr);
        atomicAdd(agg + ((size_t)(em >> 15)*NN + rc)*16 + n, v);
    }
    *(float4*)(X + n*20 + q*4) = stB;
    #pragma unroll
    for (int rr = 0; rr < 4; ++rr) {
        int em = e0 + 16 + q*4 + rr;
        float v = X[(q*4+rr)*20 + n];
        int rc = __shfl(rB, q*4 + rr);
        atomicAdd(agg + ((size_t)(em >> 15)*NN + rc)*16 + n, v);
    }
}

// ---------------------------------------------------------------------------
// node_update: 512-thr blocks (8 waves), 2 groups/wave, 256 blocks.
// ---------------------------------------------------------------------------
__global__ __launch_bounds__(512, 2) void node_update_kernel(
    const float* __restrict__ gvec,
    const float* __restrict__ agg, float* __restrict__ ve,
    const u32* __restrict__ Wp, const float* __restrict__ bin,
    const float* __restrict__ fb)
{
    __shared__ __align__(16) u32 SL[17664 + 1072];
    u32* WL = SL;
    float* WB = (float*)(SL + 17664);
    WAVE_SETUP
    stage_weights(WL, WB, Wp, bin, fb, fb + 1024, 17664, 16, threadIdx.x, 512);
    const int e0 = (blockIdx.x*8 + wid) * 32;
    const int eA = e0 + n, eB = e0 + 16 + n;
    const int bA = eA >> 15, bB = eB >> 15;
    float gA = gvec[bA], gB = gvec[bB];
    bf16x8 a[4];
    {
        float4 agv = *(const float4*)(agg + (size_t)eA*16 + q*4);
        float4 vev = *(const float4*)(ve  + (size_t)eA*16 + q*4);
        U4 c;
        c.u.x = pk2(agv.x, vev.x); c.u.y = pk2(agv.y, vev.y);
        c.u.z = pk2(agv.z, vev.z); c.u.w = pk2(agv.w, vev.w);
        a[0] = c.h;
        c.u.x = (q == 0) ? pk2(gA, 0.f) : 0u;
        c.u.y = 0u; c.u.z = 0u; c.u.w = 0u;
        a[1] = c.h;
    }
    {
        float4 agv = *(const float4*)(agg + (size_t)eB*16 + q*4);
        float4 vev = *(const float4*)(ve  + (size_t)eB*16 + q*4);
        U4 c;
        c.u.x = pk2(agv.x, vev.x); c.u.y = pk2(agv.y, vev.y);
        c.u.z = pk2(agv.z, vev.z); c.u.w = pk2(agv.w, vev.w);
        a[2] = c.h;
        c.u.x = (q == 0) ? pk2(gB, 0.f) : 0u;
        c.u.y = 0u; c.u.z = 0u; c.u.w = 0u;
        a[3] = c.h;
    }
    f32x4 OA, OB;
    mlp_core2<2, true>(a, WL, WB, n, q, OA, OB);
    float4 st;
    st.x = fmaxf(OA[0], 0.f); st.y = fmaxf(OA[1], 0.f);
    st.z = fmaxf(OA[2], 0.f); st.w = fmaxf(OA[3], 0.f);
    *(float4*)(ve + (size_t)eA*16 + q*4) = st;
    st.x = fmaxf(OB[0], 0.f); st.y = fmaxf(OB[1], 0.f);
    st.z = fmaxf(OB[2], 0.f); st.w = fmaxf(OB[3], 0.f);
    *(float4*)(ve + (size_t)eB*16 + q*4) = st;
}

// ---------------------------------------------------------------------------
// decode: 512-thr blocks (8 waves), 2 groups/wave, 256 blocks.
// ---------------------------------------------------------------------------
__global__ __launch_bounds__(512, 2) void decode_kernel(
    const float* __restrict__ ve,
    const u32* __restrict__ Wp, const float* __restrict__ bin,
    const float* __restrict__ bh, const float* __restrict__ bout,
    float* __restrict__ out)
{
    __shared__ __align__(16) u32 SL[17152 + 1072];
    u32* WL = SL;
    float* WB = (float*)(SL + 17152);
    WAVE_SETUP
    stage_weights(WL, WB, Wp, bin, bh, bout, 17152, 3, threadIdx.x, 512);
    const int e0 = (blockIdx.x*8 + wid) * 32;
    const int eA = e0 + n, eB = e0 + 16 + n;
    bf16x8 a[2];
    {
        float4 v = *(const float4*)(ve + (size_t)eA*16 + q*4);
        U4 c;
        c.u.x = pk2(v.x, 0.f); c.u.y = pk2(v.y, 0.f);
        c.u.z = pk2(v.z, 0.f); c.u.w = pk2(v.w, 0.f);
        a[0] = c.h;
    }
    {
        float4 v = *(const float4*)(ve + (size_t)eB*16 + q*4);
        U4 c;
        c.u.x = pk2(v.x, 0.f); c.u.y = pk2(v.y, 0.f);
        c.u.z = pk2(v.z, 0.f); c.u.w = pk2(v.w, 0.f);
        a[1] = c.h;
    }
    f32x4 OA, OB;
    mlp_core2<1, false>(a, WL, WB, n, q, OA, OB);
    if (q == 0) {
        out[(size_t)eA*3 + 0] = fmaxf(OA[0], 0.f);
        out[(size_t)eA*3 + 1] = fmaxf(OA[1], 0.f);
        out[(size_t)eA*3 + 2] = fmaxf(OA[2], 0.f);
        out[(size_t)eB*3 + 0] = fmaxf(OB[0], 0.f);
        out[(size_t)eB*3 + 1] = fmaxf(OB[1], 0.f);
        out[(size_t)eB*3 + 2] = fmaxf(OB[2], 0.f);
    }
}

// ---------------------------------------------------------------------------
// launch
// ---------------------------------------------------------------------------
extern "C" void kernel_launch(void* const* d_in, const int* in_sizes, int n_in,
                              void* d_out, int out_size, void* d_ws, size_t ws_size,
                              hipStream_t stream)
{
    const float* nodes     = (const float*)d_in[0];
    const float* edges     = (const float*)d_in[1];
    const float* gvec      = (const float*)d_in[2];
    const int*   senders   = (const int*)  d_in[3];
    const int*   receivers = (const int*)  d_in[4];

    const float* ne_Win  = (const float*)d_in[5];
    const float* ne_bin  = (const float*)d_in[6];
    const float* ne_Wh   = (const float*)d_in[7];
    const float* ne_bh   = (const float*)d_in[8];
    const float* ne_Wout = (const float*)d_in[9];
    const float* ne_bout = (const float*)d_in[10];

    const float* ed_Win  = (const float*)d_in[11];
    const float* ed_bin  = (const float*)d_in[12];
    const float* ed_Wh   = (const float*)d_in[13];
    const float* ed_bh   = (const float*)d_in[14];
    const float* ed_Wout = (const float*)d_in[15];
    const float* ed_bout = (const float*)d_in[16];

    const float* pe_Win  = (const float*)d_in[17];
    const float* pe_bin  = (const float*)d_in[18];
    const float* pe_Wh   = (const float*)d_in[19];
    const float* pe_bh   = (const float*)d_in[20];
    const float* pe_Wout = (const float*)d_in[21];
    const float* pe_bout = (const float*)d_in[22];
    const float* pe_lng  = (const float*)d_in[23];
    const float* pe_lnb  = (const float*)d_in[24];

    const float* pv_Win  = (const float*)d_in[25];
    const float* pv_bin  = (const float*)d_in[26];
    const float* pv_Wh   = (const float*)d_in[27];
    const float* pv_bh   = (const float*)d_in[28];
    const float* pv_Wout = (const float*)d_in[29];
    const float* pv_bout = (const float*)d_in[30];
    const float* pv_lng  = (const float*)d_in[31];
    const float* pv_lnb  = (const float*)d_in[32];

    const float* de_Win  = (const float*)d_in[33];
    const float* de_bin  = (const float*)d_in[34];
    const float* de_Wh   = (const float*)d_in[35];
    const float* de_bh   = (const float*)d_in[36];
    const float* de_Wout = (const float*)d_in[37];
    const float* de_bout = (const float*)d_in[38];

    // workspace: ve | ee | agg (4 MB each) | packed bf16 weights | folded biases
    float* ve  = (float*)d_ws;
    float* ee  = ve + (size_t)1048576;
    float* agg = ee + (size_t)1048576;
    u32* Wne = (u32*)(agg + (size_t)1048576);
    u32* Wed = Wne + 17152;
    u32* Wpe = Wed + 17152;
    u32* Wpv = Wpe + 17664;
    u32* Wde = Wpv + 17664;
    float* Fpe = (float*)(Wde + 17152);
    float* Fpv = Fpe + 1040;

    prep_kernel<<<360, dim3(256), 0, stream>>>(
        ne_Win, ne_Wh, ne_Wout,
        ed_Win, ed_Wh, ed_Wout,
        pe_Win, pe_Wh, pe_Wout, pe_lng, pe_lnb, pe_bh, pe_bout,
        pv_Win, pv_Wh, pv_Wout, pv_lng, pv_lnb, pv_bh, pv_bout,
        de_Win, de_Wh, de_Wout,
        Wne, Wed, Wpe, Wpv, Wde, Fpe, Fpv);

    encode_kernel<<<512, dim3(512), 0, stream>>>(nodes, edges, gvec, senders, receivers,
        Wne, ne_bin, ne_bh, ne_bout,
        Wed, ed_bin, ed_bh, ed_bout, ve, ee);

    for (int step = 0; step < 2; ++step) {
        hipMemsetAsync(agg, 0, (size_t)BB * NN * 16 * sizeof(float), stream);
        edge_update_kernel<<<256, dim3(512), 0, stream>>>(gvec, senders, receivers,
            ve, ee, agg, Wpe, pe_bin, Fpe);
        node_update_kernel<<<256, dim3(512), 0, stream>>>(gvec, agg, ve,
            Wpv, pv_bin, Fpv);
    }

    decode_kernel<<<256, dim3(512), 0, stream>>>(ve,
        Wde, de_bin, de_bh, de_bout, (float*)d_out);
}

// Round 13
// 290.728 us; speedup vs baseline: 1.1903x; 1.0445x over previous
//
#include <hip/hip_runtime.h>

#define BB 2
#define NN 32768
#define EN 32768

typedef unsigned int u32;
typedef __attribute__((ext_vector_type(8)))  short bf16x8;
typedef __attribute__((ext_vector_type(2)))  float f32x2;
typedef __attribute__((ext_vector_type(16))) float f32x16;

union U4 { uint4 u; bf16x8 h; };

#if defined(__has_builtin)
#if __has_builtin(__builtin_amdgcn_cvt_pk_bf16_f32)
#define HAVE_CVT_PK 1
#endif
#endif

#ifdef HAVE_CVT_PK
typedef __attribute__((ext_vector_type(2))) __bf16 bfv2;
__device__ __forceinline__ u32 pk2(float lo, float hi) {
    bfv2 v = __builtin_amdgcn_cvt_pk_bf16_f32(lo, hi);
    return __builtin_bit_cast(u32, v);
}
#else
__device__ __forceinline__ u32 pk2(float lo, float hi) {
    u32 a = __builtin_bit_cast(u32, lo);
    u32 b = __builtin_bit_cast(u32, hi);
    a += 0x7FFFu + ((a >> 16) & 1u);
    b += 0x7FFFu + ((b >> 16) & 1u);
    return (a >> 16) | (b & 0xFFFF0000u);
}
#endif

__device__ __forceinline__ f32x16 MF32(bf16x8 a, bf16x8 b, f32x16 c) {
    return __builtin_amdgcn_mfma_f32_32x32x16_bf16(a, b, c, 0, 0, 0);
}

// ---------------------------------------------------------------------------
// 32x32 MFMA engine. Lane (e = lane&31, h = lane>>5).
// C/D: col = e (element), row(r,h) = (r&3) + 8*(r>>2) + 4h  [verified layout].
// k-slot -> feature permutation: f(t,h,j) = 16t + 4h + (j&3) + 8*(j>>2).
// Under this pi, C-reg r maps to B-frag (t = r>>3, pos j = r&7) identically:
// layer-to-layer is pure registers. LN partner = single shfl_xor(32).
// Weights are the A operand (lane = out-feature m), biases enter via MFMA C.
// ---------------------------------------------------------------------------
template<bool LN>
__device__ __forceinline__ void transform32(f32x16 D, bf16x8& B0, bf16x8& B1)
{
    f32x2 p0 = {D[0],D[1]},  p1 = {D[2],D[3]},  p2 = {D[4],D[5]},  p3 = {D[6],D[7]};
    f32x2 p4 = {D[8],D[9]},  p5 = {D[10],D[11]},p6 = {D[12],D[13]},p7 = {D[14],D[15]};
    const f32x2 zz = {0.f, 0.f};
    p0 = __builtin_elementwise_max(p0, zz); p1 = __builtin_elementwise_max(p1, zz);
    p2 = __builtin_elementwise_max(p2, zz); p3 = __builtin_elementwise_max(p3, zz);
    p4 = __builtin_elementwise_max(p4, zz); p5 = __builtin_elementwise_max(p5, zz);
    p6 = __builtin_elementwise_max(p6, zz); p7 = __builtin_elementwise_max(p7, zz);
    if (LN) {
        f32x2 sv = ((p0+p1)+(p2+p3)) + ((p4+p5)+(p6+p7));
        f32x2 tv = __builtin_elementwise_fma(p0,p0,
                   __builtin_elementwise_fma(p1,p1,
                   __builtin_elementwise_fma(p2,p2,
                   __builtin_elementwise_fma(p3,p3,
                   __builtin_elementwise_fma(p4,p4,
                   __builtin_elementwise_fma(p5,p5,
                   __builtin_elementwise_fma(p6,p6, p7*p7)))))));
        float s = sv.x + sv.y;
        float t = tv.x + tv.y;
        s += __shfl_xor(s, 32);
        t += __shfl_xor(t, 32);
        float mu  = s * (1.f/32.f);
        float var = fmaf(-mu, mu, t * (1.f/32.f));
        float rs  = rsqrtf(var + 1e-5f);
        float nt  = -mu * rs;
        f32x2 rs2 = {rs, rs}, nt2 = {nt, nt};
        p0 = __builtin_elementwise_fma(p0, rs2, nt2);
        p1 = __builtin_elementwise_fma(p1, rs2, nt2);
        p2 = __builtin_elementwise_fma(p2, rs2, nt2);
        p3 = __builtin_elementwise_fma(p3, rs2, nt2);
        p4 = __builtin_elementwise_fma(p4, rs2, nt2);
        p5 = __builtin_elementwise_fma(p5, rs2, nt2);
        p6 = __builtin_elementwise_fma(p6, rs2, nt2);
        p7 = __builtin_elementwise_fma(p7, rs2, nt2);
    }
    U4 c;
    c.u.x = pk2(p0.x,p0.y); c.u.y = pk2(p1.x,p1.y);
    c.u.z = pk2(p2.x,p2.y); c.u.w = pk2(p3.x,p3.y);
    B0 = c.h;
    c.u.x = pk2(p4.x,p4.y); c.u.y = pk2(p5.x,p5.y);
    c.u.z = pk2(p6.x,p6.y); c.u.w = pk2(p7.x,p7.y);
    B1 = c.h;
}

// Bias as MFMA C operand: WB[base + h*16 + r] = b[row(r,h)] (pre-permuted at
// staging). All lanes of a half read the same addrs -> LDS broadcast (free).
__device__ __forceinline__ f32x16 load_biasC(const float* WB, int base, int h) {
    const float4* p = (const float4*)(WB + base + h*16);
    float4 a = p[0], b = p[1], c = p[2], d = p[3];
    f32x16 C = {a.x,a.y,a.z,a.w, b.x,b.y,b.z,b.w,
                c.x,c.y,c.z,c.w, d.x,d.y,d.z,d.w};
    return C;
}

// ---------------------------------------------------------------------------
// Wave-level deep MLP on one 32-element group. Weight LDS reads are plain
// per-lane contiguous (addr = base + lane*4 dwords) -> conflict-free.
// Depth-2 weight prefetch, depth-1 bias prefetch.
// WL (dwords): [Bin NT*256][Bh 32*512][Bo 512]
// ---------------------------------------------------------------------------
template<int NT, bool LN>
__device__ __forceinline__ f32x16 mlp32(const bf16x8* bIn,
    const u32* WL, const float* WB, int lane, int h)
{
    constexpr int HB = NT*256;
    constexpr int BO = HB + 16384;
    U4 c;
    f32x16 D = load_biasC(WB, 0, h);
    #pragma unroll
    for (int t = 0; t < NT; ++t) {
        c.u = *(const uint4*)(WL + t*256 + lane*4);
        D = MF32(c.h, bIn[t], D);
    }
    c.u = *(const uint4*)(WL + HB + lane*4);        bf16x8 w0 = c.h;
    c.u = *(const uint4*)(WL + HB + 256 + lane*4);  bf16x8 w1 = c.h;
    c.u = *(const uint4*)(WL + HB + 512 + lane*4);  bf16x8 x0 = c.h;
    c.u = *(const uint4*)(WL + HB + 768 + lane*4);  bf16x8 x1 = c.h;
    f32x16 pb = load_biasC(WB, 32, h);
    bf16x8 B0, B1;
    transform32<LN>(D, B0, B1);
    #pragma unroll 1
    for (int l = 0; l < 32; ++l) {
        const int lp = (l+2 < 32) ? l+2 : 31;
        c.u = *(const uint4*)(WL + HB + lp*512 + lane*4);       bf16x8 nw0 = c.h;
        c.u = *(const uint4*)(WL + HB + lp*512 + 256 + lane*4); bf16x8 nw1 = c.h;
        const int lb_ = (l+1 < 32) ? l+1 : 31;
        f32x16 nb = load_biasC(WB, 32 + lb_*32, h);
        f32x16 E = MF32(w0, B0, pb);
        E = MF32(w1, B1, E);
        transform32<LN>(E, B0, B1);
        w0 = x0; w1 = x1; x0 = nw0; x1 = nw1; pb = nb;
    }
    c.u = *(const uint4*)(WL + BO + lane*4);        bf16x8 o0 = c.h;
    c.u = *(const uint4*)(WL + BO + 256 + lane*4);  bf16x8 o1 = c.h;
    f32x16 Co = load_biasC(WB, 1056, h);
    f32x16 O = MF32(o0, B0, Co);
    O = MF32(o1, B1, O);
    return O;
}

// ---------------------------------------------------------------------------
// Block-level staging: weights copied linearly; biases permuted to the
// C-operand layout WB[region + h*16 + r] = b[(r&3)+8*(r>>2)+4h].
// WB (floats): [0..32) bin | [32..1056) hidden | [1056..1088) out
// ---------------------------------------------------------------------------
__device__ __forceinline__ void stage_weights32(
    u32* WL, float* WB, const u32* __restrict__ Wp,
    const float* __restrict__ bin, const float* __restrict__ bhid,
    const float* __restrict__ bo, int wtot, int nbo, int tid, int nthr)
{
    for (int C = tid*4; C < wtot; C += nthr*4)
        *(uint4*)(WL + C) = *(const uint4*)(Wp + C);
    for (int i = tid; i < 1088; i += nthr) {
        float v;
        if (i < 32) {
            int w = i, hh = w>>4, r = w&15;
            int f = (r&3) + 8*(r>>2) + 4*hh;
            v = bin[f];
        } else if (i < 1056) {
            int l = (i-32)>>5, w = (i-32)&31, hh = w>>4, r = w&15;
            int f = (r&3) + 8*(r>>2) + 4*hh;
            v = bhid[l*32 + f];
        } else {
            int w = i-1056, hh = w>>4, r = w&15;
            int f = (r&3) + 8*(r>>2) + 4*hh;
            v = (f < nbo) ? bo[f] : 0.f;
        }
        WB[i] = v;
    }
    __syncthreads();
}

// ---------------------------------------------------------------------------
// Weight packing to the 32x32 pi layout + LN-gamma fold, one prep kernel.
// Per t-chunk: dword index = (t*64 + lane)*4 + d, lane = h*32 + m;
// dword = pk2(W[f0][m], W[f0+1][m]), f0 = 16t + 4h + 2*(d&1) + 8*(d>>1).
// ---------------------------------------------------------------------------
__device__ __forceinline__ void pack_body32(
    const float* __restrict__ Win, const float* __restrict__ Wh,
    const float* __restrict__ Wout, const float* __restrict__ lng,
    u32* __restrict__ dst, int din, int dout, int NT, int lb, int tid)
{
    int t = lb * 256 + tid;
    int binW = NT * 256;
    int tot = binW + 16384 + 512;
    if (t >= tot) return;
    float lo, hi;
    if (t < binW) {
        int tt = t>>8, rem = t&255, ln_ = rem>>2, d = rem&3;
        int hh = ln_>>5, m = ln_&31;
        int f0 = 16*tt + 4*hh + 2*(d&1) + 8*(d>>1);
        lo = (f0   < din) ? Win[f0*32 + m]     : 0.f;
        hi = (f0+1 < din) ? Win[(f0+1)*32 + m] : 0.f;
    } else if (t < binW + 16384) {
        int u = t - binW, l = u>>9, v = u&511;
        int tt = v>>8, rem = v&255, ln_ = rem>>2, d = rem&3;
        int hh = ln_>>5, m = ln_&31;
        int f0 = 16*tt + 4*hh + 2*(d&1) + 8*(d>>1);
        lo = Wh[l*1024 + f0*32 + m];
        hi = Wh[l*1024 + (f0+1)*32 + m];
        if (lng) { lo *= lng[l*32 + f0]; hi *= lng[l*32 + f0 + 1]; }
    } else {
        int u = t - binW - 16384;
        int tt = u>>8, rem = u&255, ln_ = rem>>2, d = rem&3;
        int hh = ln_>>5, m = ln_&31;
        int f0 = 16*tt + 4*hh + 2*(d&1) + 8*(d>>1);
        lo = (m < dout) ? Wout[f0*dout + m]     : 0.f;
        hi = (m < dout) ? Wout[(f0+1)*dout + m] : 0.f;
        if (lng) { lo *= lng[1024 + f0]; hi *= lng[1024 + f0 + 1]; }
    }
    dst[t] = pk2(lo, hi);
}

__device__ __forceinline__ void fold_body(
    const float* __restrict__ Wh,   const float* __restrict__ bh,
    const float* __restrict__ Wout, const float* __restrict__ bout,
    const float* __restrict__ lnb,  float* __restrict__ fb, int lb, int tid)
{
    int j = lb * 256 + tid;
    if (j < 1024) {
        int l = j >> 5, jj = j & 31;
        float acc = bh[j];
        #pragma unroll
        for (int k = 0; k < 32; ++k)
            acc = fmaf(lnb[l*32 + k], Wh[l*1024 + k*32 + jj], acc);
        fb[j] = acc;
    } else if (j < 1024 + 16) {
        int jj = j - 1024;
        float acc = bout[jj];
        #pragma unroll
        for (int k = 0; k < 32; ++k)
            acc = fmaf(lnb[1024 + k], Wout[k*16 + jj], acc);
        fb[j] = acc;
    }
}

__global__ __launch_bounds__(256) void prep_kernel(
    const float* ne_Win, const float* ne_Wh, const float* ne_Wout,
    const float* ed_Win, const float* ed_Wh, const float* ed_Wout,
    const float* pe_Win, const float* pe_Wh, const float* pe_Wout,
    const float* pe_lng, const float* pe_lnb, const float* pe_bh, const float* pe_bout,
    const float* pv_Win, const float* pv_Wh, const float* pv_Wout,
    const float* pv_lng, const float* pv_lnb, const float* pv_bh, const float* pv_bout,
    const float* de_Win, const float* de_Wh, const float* de_Wout,
    u32* Wne, u32* Wed, u32* Wpe, u32* Wpv, u32* Wde,
    float* Fpe, float* Fpv)
{
    int bx = blockIdx.x, tid = threadIdx.x;
    if      (bx < 67)  pack_body32(ne_Win, ne_Wh, ne_Wout, nullptr, Wne,  7, 16, 1, bx,       tid);
    else if (bx < 134) pack_body32(ed_Win, ed_Wh, ed_Wout, nullptr, Wed,  5, 16, 1, bx - 67,  tid);
    else if (bx < 204) pack_body32(pe_Win, pe_Wh, pe_Wout, pe_lng,  Wpe, 49, 16, 4, bx - 134, tid);
    else if (bx < 273) pack_body32(pv_Win, pv_Wh, pv_Wout, pv_lng,  Wpv, 33, 16, 3, bx - 204, tid);
    else if (bx < 340) pack_body32(de_Win, de_Wh, de_Wout, nullptr, Wde, 16,  3, 1, bx - 273, tid);
    else if (bx < 345) fold_body(pe_Wh, pe_bh, pe_Wout, pe_bout, pe_lnb, Fpe, bx - 340, tid);
    else               fold_body(pv_Wh, pv_bh, pv_Wout, pv_bout, pv_lnb, Fpv, bx - 345, tid);
}

// Pack one 16-feature array chunk into a B-frag: lane-half h takes features
// {4h+0..3, 4h+8..11} of its element -> float4 at +h*4 and +h*4+8.
__device__ __forceinline__ bf16x8 stage_chunk(const float* __restrict__ arr,
                                              size_t e, int h)
{
    const int off = h*4;
    float4 a = *(const float4*)(arr + e*16 + off);
    float4 b = *(const float4*)(arr + e*16 + off + 8);
    U4 c;
    c.u.x = pk2(a.x, a.y); c.u.y = pk2(a.z, a.w);
    c.u.z = pk2(b.x, b.y); c.u.w = pk2(b.z, b.w);
    return c.h;
}

#define WAVE_SETUP \
    const int lane = threadIdx.x & 63; \
    const int wid  = threadIdx.x >> 6; \
    const int el = lane & 31, h = lane >> 5;

// ---------------------------------------------------------------------------
// encode: 512-thr blocks (8 waves x 32 elems), 512 blocks -> 2 blocks/CU.
// ---------------------------------------------------------------------------
__global__ __launch_bounds__(512, 4) void encode_kernel(
    const float* __restrict__ nodes, const float* __restrict__ edges,
    const float* __restrict__ gvec,
    const int* __restrict__ senders, const int* __restrict__ receivers,
    const u32* __restrict__ Wne, const float* __restrict__ ne_bin,
    const float* __restrict__ ne_bh, const float* __restrict__ ne_bout,
    const u32* __restrict__ Wed, const float* __restrict__ ed_bin,
    const float* __restrict__ ed_bh, const float* __restrict__ ed_bout,
    float* __restrict__ ve, float* __restrict__ ee)
{
    __shared__ __align__(16) u32 SL[17152 + 1088];
    u32* WL = SL;
    float* WB = (float*)(SL + 17152);
    WAVE_SETUP
    const bool edge_stage = blockIdx.x >= 256;
    stage_weights32(WL, WB,
                    edge_stage ? Wed : Wne,
                    edge_stage ? ed_bin : ne_bin,
                    edge_stage ? ed_bh : ne_bh,
                    edge_stage ? ed_bout : ne_bout,
                    17152, 16, threadIdx.x, 512);
    const int lb = edge_stage ? (blockIdx.x - 256) : blockIdx.x;
    const int e = (lb*8 + wid)*32 + el;
    const int b = e >> 15;
    bf16x8 a0;
    {
        uint4 w; w.x = 0u; w.y = 0u; w.z = 0u; w.w = 0u;
        if (!edge_stage) {
            // x = [nodes(6), g] -> features 0..6
            if (h == 0) {
                float2 v01 = *(const float2*)(nodes + (size_t)e*6);
                float2 v23 = *(const float2*)(nodes + (size_t)e*6 + 2);
                w.x = pk2(v01.x, v01.y); w.y = pk2(v23.x, v23.y);
            } else {
                float2 v45 = *(const float2*)(nodes + (size_t)e*6 + 4);
                w.x = pk2(v45.x, v45.y); w.y = pk2(gvec[b], 0.f);
            }
        } else {
            // x = [edge, rel0..2, nrm] -> features 0..4
            int s = senders[e], r = receivers[e];
            const float* ps = nodes + ((size_t)b*NN + s)*6;
            const float* pr = nodes + ((size_t)b*NN + r)*6;
            float2 s01 = *(const float2*)ps; float s2v = ps[2];
            float2 r01 = *(const float2*)pr; float r2v = pr[2];
            float r0 = s01.x - r01.x, r1 = s01.y - r01.y, r2 = s2v - r2v;
            if (h == 0) {
                w.x = pk2(edges[e], r0); w.y = pk2(r1, r2);
            } else {
                w.x = pk2(sqrtf(r0*r0 + r1*r1 + r2*r2), 0.f);
            }
        }
        U4 c; c.u = w; a0 = c.h;
    }
    float* dst = edge_stage ? ee : ve;
    f32x16 O = mlp32<1, false>(&a0, WL, WB, lane, h);
    float4 s1, s2;
    s1.x = fmaxf(O[0], 0.f); s1.y = fmaxf(O[1], 0.f);
    s1.z = fmaxf(O[2], 0.f); s1.w = fmaxf(O[3], 0.f);
    s2.x = fmaxf(O[4], 0.f); s2.y = fmaxf(O[5], 0.f);
    s2.z = fmaxf(O[6], 0.f); s2.w = fmaxf(O[7], 0.f);
    *(float4*)(dst + (size_t)e*16 + h*4)     = s1;
    *(float4*)(dst + (size_t)e*16 + h*4 + 8) = s2;
}

// ---------------------------------------------------------------------------
// edge_update: 512-thr blocks (8 waves x 32 elems), 256 blocks.
// ---------------------------------------------------------------------------
__global__ __launch_bounds__(512, 2) void edge_update_kernel(
    const float* __restrict__ gvec,
    const int* __restrict__ senders, const int* __restrict__ receivers,
    const float* __restrict__ ve, float* __restrict__ ee, float* __restrict__ agg,
    const u32* __restrict__ Wp, const float* __restrict__ bin,
    const float* __restrict__ fb)
{
    __shared__ __align__(16) u32 SL[17920 + 1088 + 8*544];
    u32* WL = SL;
    float* WB = (float*)(SL + 17920);
    WAVE_SETUP
    float* X = (float*)(SL + 19008) + wid*544;
    stage_weights32(WL, WB, Wp, bin, fb, fb + 1024, 17920, 16, threadIdx.x, 512);
    const int e0 = (blockIdx.x*8 + wid)*32;
    const int e  = e0 + el;
    const int b  = e >> 15;
    const int s  = senders[e], r_ = receivers[e];
    bf16x8 a[4];
    a[0] = stage_chunk(ee, (size_t)e, h);
    a[1] = stage_chunk(ve, (size_t)b*NN + s, h);
    a[2] = stage_chunk(ve, (size_t)b*NN + r_, h);
    {
        uint4 w; w.x = (h == 0) ? pk2(gvec[b], 0.f) : 0u;
        w.y = 0u; w.z = 0u; w.w = 0u;
        U4 c; c.u = w; a[3] = c.h;
    }
    f32x16 O = mlp32<4, true>(a, WL, WB, lane, h);
    float4 s1, s2;
    s1.x = fmaxf(O[0], 0.f); s1.y = fmaxf(O[1], 0.f);
    s1.z = fmaxf(O[2], 0.f); s1.w = fmaxf(O[3], 0.f);
    s2.x = fmaxf(O[4], 0.f); s2.y = fmaxf(O[5], 0.f);
    s2.z = fmaxf(O[6], 0.f); s2.w = fmaxf(O[7], 0.f);
    *(float4*)(ee + (size_t)e*16 + h*4)     = s1;
    *(float4*)(ee + (size_t)e*16 + h*4 + 8) = s2;
    // Transpose through wave-private LDS so each atomic instruction hits 4
    // receiver lines (16 lanes share a receiver).
    *(float4*)(X + el*17 + h*4)     = s1;
    *(float4*)(X + el*17 + h*4 + 8) = s2;
    const int feat = lane & 15;
    #pragma unroll
    for (int rr = 0; rr < 8; ++rr) {
        int m = (lane >> 4)*8 + rr;            // element index within group
        float v = X[m*17 + feat];
        int rc = __shfl(r_, m);                // lane m (h=0) holds receivers
        int eg = e0 + m;
        atomicAdd(agg + ((size_t)(eg >> 15)*NN + rc)*16 + feat, v);
    }
}

// ---------------------------------------------------------------------------
// node_update: 512-thr blocks (8 waves x 32 elems), 256 blocks.
// DEC=true (step 2): fuses decode — node-output regs 0..7 ARE decode's input
// B-frag under the pi layout (identity map); writes d_out, skips ve store.
// ---------------------------------------------------------------------------
template<bool DEC>
__global__ __launch_bounds__(512, 2) void node_update_kernel(
    const float* __restrict__ gvec,
    const float* __restrict__ agg, float* __restrict__ ve,
    const u32* __restrict__ Wp, const float* __restrict__ bin,
    const float* __restrict__ fb,
    const u32* __restrict__ Wde, const float* __restrict__ de_bin,
    const float* __restrict__ de_bh, const float* __restrict__ de_bout,
    float* __restrict__ out)
{
    __shared__ __align__(16) u32 SL[DEC ? (18752 + 17152 + 1088) : 18752];
    u32* WL = SL;
    float* WB = (float*)(SL + 17664);
    u32* WL2 = SL + 18752;
    float* WB2 = (float*)(SL + 18752 + 17152);
    WAVE_SETUP
    stage_weights32(WL, WB, Wp, bin, fb, fb + 1024, 17664, 16, threadIdx.x, 512);
    if (DEC)
        stage_weights32(WL2, WB2, Wde, de_bin, de_bh, de_bout, 17152, 3, threadIdx.x, 512);
    const int e = (blockIdx.x*8 + wid)*32 + el;
    const int b = e >> 15;
    bf16x8 a[3];
    a[0] = stage_chunk(agg, (size_t)e, h);
    a[1] = stage_chunk(ve,  (size_t)e, h);
    {
        uint4 w; w.x = (h == 0) ? pk2(gvec[b], 0.f) : 0u;
        w.y = 0u; w.z = 0u; w.w = 0u;
        U4 c; c.u = w; a[2] = c.h;
    }
    f32x16 O = mlp32<3, true>(a, WL, WB, lane, h);
    if (!DEC) {
        float4 s1, s2;
        s1.x = fmaxf(O[0], 0.f); s1.y = fmaxf(O[1], 0.f);
        s1.z = fmaxf(O[2], 0.f); s1.w = fmaxf(O[3], 0.f);
        s2.x = fmaxf(O[4], 0.f); s2.y = fmaxf(O[5], 0.f);
        s2.z = fmaxf(O[6], 0.f); s2.w = fmaxf(O[7], 0.f);
        *(float4*)(ve + (size_t)e*16 + h*4)     = s1;
        *(float4*)(ve + (size_t)e*16 + h*4 + 8) = s2;
    } else {
        bf16x8 D0, D1;
        transform32<false>(O, D0, D1);   // relu + pack; D1 is all-zero rows
        f32x16 O2 = mlp32<1, false>(&D0, WL2, WB2, lane, h);
        if (h == 0) {
            out[(size_t)e*3 + 0] = fmaxf(O2[0], 0.f);
            out[(size_t)e*3 + 1] = fmaxf(O2[1], 0.f);
            out[(size_t)e*3 + 2] = fmaxf(O2[2], 0.f);
        }
    }
}

// ---------------------------------------------------------------------------
// launch
// ---------------------------------------------------------------------------
extern "C" void kernel_launch(void* const* d_in, const int* in_sizes, int n_in,
                              void* d_out, int out_size, void* d_ws, size_t ws_size,
                              hipStream_t stream)
{
    const float* nodes     = (const float*)d_in[0];
    const float* edges     = (const float*)d_in[1];
    const float* gvec      = (const float*)d_in[2];
    const int*   senders   = (const int*)  d_in[3];
    const int*   receivers = (const int*)  d_in[4];

    const float* ne_Win  = (const float*)d_in[5];
    const float* ne_bin  = (const float*)d_in[6];
    const float* ne_Wh   = (const float*)d_in[7];
    const float* ne_bh   = (const float*)d_in[8];
    const float* ne_Wout = (const float*)d_in[9];
    const float* ne_bout = (const float*)d_in[10];

    const float* ed_Win  = (const float*)d_in[11];
    const float* ed_bin  = (const float*)d_in[12];
    const float* ed_Wh   = (const float*)d_in[13];
    const float* ed_bh   = (const float*)d_in[14];
    const float* ed_Wout = (const float*)d_in[15];
    const float* ed_bout = (const float*)d_in[16];

    const float* pe_Win  = (const float*)d_in[17];
    const float* pe_bin  = (const float*)d_in[18];
    const float* pe_Wh   = (const float*)d_in[19];
    const float* pe_bh   = (const float*)d_in[20];
    const float* pe_Wout = (const float*)d_in[21];
    const float* pe_bout = (const float*)d_in[22];
    const float* pe_lng  = (const float*)d_in[23];
    const float* pe_lnb  = (const float*)d_in[24];

    const float* pv_Win  = (const float*)d_in[25];
    const float* pv_bin  = (const float*)d_in[26];
    const float* pv_Wh   = (const float*)d_in[27];
    const float* pv_bh   = (const float*)d_in[28];
    const float* pv_Wout = (const float*)d_in[29];
    const float* pv_bout = (const float*)d_in[30];
    const float* pv_lng  = (const float*)d_in[31];
    const float* pv_lnb  = (const float*)d_in[32];

    const float* de_Win  = (const float*)d_in[33];
    const float* de_bin  = (const float*)d_in[34];
    const float* de_Wh   = (const float*)d_in[35];
    const float* de_bh   = (const float*)d_in[36];
    const float* de_Wout = (const float*)d_in[37];
    const float* de_bout = (const float*)d_in[38];

    // workspace: ve | ee | agg0 | agg1 (4 MB each) | packed weights | biases
    float* ve   = (float*)d_ws;
    float* ee   = ve   + (size_t)1048576;
    float* agg0 = ee   + (size_t)1048576;
    float* agg1 = agg0 + (size_t)1048576;
    u32* Wne = (u32*)(agg1 + (size_t)1048576);
    u32* Wed = Wne + 17152;
    u32* Wpe = Wed + 17152;
    u32* Wpv = Wpe + 17920;
    u32* Wde = Wpv + 17664;
    float* Fpe = (float*)(Wde + 17152);
    float* Fpv = Fpe + 1040;

    prep_kernel<<<350, dim3(256), 0, stream>>>(
        ne_Win, ne_Wh, ne_Wout,
        ed_Win, ed_Wh, ed_Wout,
        pe_Win, pe_Wh, pe_Wout, pe_lng, pe_lnb, pe_bh, pe_bout,
        pv_Win, pv_Wh, pv_Wout, pv_lng, pv_lnb, pv_bh, pv_bout,
        de_Win, de_Wh, de_Wout,
        Wne, Wed, Wpe, Wpv, Wde, Fpe, Fpv);

    // zero both agg ping-pong buffers in one shot
    hipMemsetAsync(agg0, 0, (size_t)2 * 1048576 * sizeof(float), stream);

    encode_kernel<<<512, dim3(512), 0, stream>>>(nodes, edges, gvec, senders, receivers,
        Wne, ne_bin, ne_bh, ne_bout,
        Wed, ed_bin, ed_bh, ed_bout, ve, ee);

    // step 0
    edge_update_kernel<<<256, dim3(512), 0, stream>>>(gvec, senders, receivers,
        ve, ee, agg0, Wpe, pe_bin, Fpe);
    node_update_kernel<false><<<256, dim3(512), 0, stream>>>(gvec, agg0, ve,
        Wpv, pv_bin, Fpv, Wde, de_bin, de_bh, de_bout, (float*)d_out);
    // step 1 (+ fused decode)
    edge_update_kernel<<<256, dim3(512), 0, stream>>>(gvec, senders, receivers,
        ve, ee, agg1, Wpe, pe_bin, Fpe);
    node_update_kernel<true><<<256, dim3(512), 0, stream>>>(gvec, agg1, ve,
        Wpv, pv_bin, Fpv, Wde, de_bin, de_bh, de_bout, (float*)d_out);
}